// Round 4
// baseline (5854.438 us; speedup 1.0000x reference)
//
#include <hip/hip_runtime.h>
#include <hip/hip_bf16.h>
#include <math.h>

#define TT 256
#define BB 256
#define DP1 129
#define HH 512
#define K1 1280
#define DD 128
#define RTOT 65280   // B*(T-1)
#define XKP 144      // padded x-part K (129 feats + 1 bias + 14 zero)
#define HKP 528      // padded h-part K (512 h + 1 bias + 15 zero)

// ---- ws layout ----
// float region:
#define OFF_W1T 0            // 513*1280
#define OFF_W2T 656640       // 1280*128
#define F_END   820480
// bf16 region (offsets in elements, base = (bf16*)(ws + F_END)):
#define U_X16   0            // 65536*144
#define U_WHF   9437184      // 48*33*512
#define U_WXF   10248192     // 48*9*512
#define U_H0    10469376     // 256*528
#define U_HIST  10604544     // 256*256*528
#define U_BAR   45207552     // 128 ints (8 groups x 64B spacing), as int* into bf16 region
// out layout (floats)
#define OUT_DIST 8355840     // 256*255*128
#define OUT_LEN  8356608

typedef __attribute__((ext_vector_type(8))) short bf16x8;
typedef __attribute__((ext_vector_type(16))) float f32x16;

__device__ __forceinline__ float sigm(float v) { return 1.0f / (1.0f + __expf(-v)); }

// One-time pack: fp32 head weights transposed + bf16 x (with bias col) +
// GRU weights in exact MFMA B-fragment order (lane-contiguous) + h0 + barrier init.
__global__ __launch_bounds__(256) void prep_kernel(
    const float* __restrict__ x, const float* __restrict__ h0,
    const float* __restrict__ w_ih, const float* __restrict__ w_hh,
    const float* __restrict__ b_ih, const float* __restrict__ b_hh,
    const float* __restrict__ w1, const float* __restrict__ w2,
    float* __restrict__ ws)
{
    __hip_bfloat16* bf = (__hip_bfloat16*)(ws + F_END);
    int i = blockIdx.x * 256 + threadIdx.x;
    if (i < 656640) {                         // w1T[k][kc] = w1[kc][k]
        int k = i / K1, kc = i - k * K1;
        ws[OFF_W1T + i] = w1[kc * 513 + k];
    } else if (i < 820480) {                  // w2T[kc][d] = w2[d][kc]
        int r = i - 656640;
        int kc = r / DD, d = r - kc * DD;
        ws[OFF_W2T + r] = w2[d * K1 + kc];
    } else if (i < 10257664) {                // x16: (t*B+b, 144)
        int r = i - 820480;
        int tb = r / XKP, k = r - tb * XKP;
        float v = (k < DP1) ? x[(size_t)tb * DP1 + k] : (k == DP1 ? 1.0f : 0.0f);
        bf[U_X16 + r] = __float2bfloat16(v);
    } else if (i < 11068672) {                // whf B-frags (K=528 incl b_hh row)
        int r = i - 10257664;
        int e = r & 7;
        int lane = (r >> 3) & 63;
        int rem = r >> 9;
        int kc = rem % 33, gi = rem / 33;
        int jb = gi / 3, g = gi - jb * 3;
        int j = jb * 32 + (lane & 31);
        int k = kc * 16 + (lane >> 5) * 8 + e;
        float v = (k < HH) ? w_hh[(size_t)(g * HH + j) * HH + k]
                : (k == HH ? b_hh[g * HH + j] : 0.0f);
        bf[U_WHF + r] = __float2bfloat16(v);
    } else if (i < 11289856) {                // wxf B-frags (K=144 incl b_ih row)
        int r = i - 11068672;
        int e = r & 7;
        int lane = (r >> 3) & 63;
        int rem = r >> 9;
        int kc = rem % 9, gi = rem / 9;
        int jb = gi / 3, g = gi - jb * 3;
        int j = jb * 32 + (lane & 31);
        int k = kc * 16 + (lane >> 5) * 8 + e;
        float v = (k < DP1) ? w_ih[(size_t)(g * HH + j) * DP1 + k]
                : (k == DP1 ? b_ih[g * HH + j] : 0.0f);
        bf[U_WXF + r] = __float2bfloat16(v);
    } else if (i < 11425024) {                // h0 padded (B, 528)
        int r = i - 11289856;
        int b = r / HKP, k = r - b * HKP;
        float v = (k < HH) ? h0[(size_t)b * HH + k] : (k == HH ? 1.0f : 0.0f);
        bf[U_H0 + r] = __float2bfloat16(v);
    } else if (i < 11425152) {                // zero barrier counters (re-poisoned ws!)
        ((int*)(bf + U_BAR))[i - 11425024] = 0;
    }
}

// Persistent GRU scan: one kernel, 256 timesteps. Grid (8 bt, 16 jblk) = 128
// blocks, all co-resident (1 block/CU). Waves 0/1/2 = gates r/z/n; B-frags
// held in REGISTERS for the whole scan (42 x bf16x8 = 168 VGPRs/lane).
// Batch-tile groups (16 blocks sharing bt) sync via their own monotone
// atomic counter; x A-frags for t+1 prefetched during the barrier wait.
__global__ __launch_bounds__(256, 1) void gru_scan(
    const __hip_bfloat16* __restrict__ x16,
    const __hip_bfloat16* __restrict__ h0p,
    __hip_bfloat16* __restrict__ hist,
    const __hip_bfloat16* __restrict__ whf,
    const __hip_bfloat16* __restrict__ wxf,
    const int* __restrict__ lengths,
    int* __restrict__ bar)
{
    __shared__ float p[4][32][33];   // r, z, xn, hn preacts (+1 pad col)
    const int tid  = threadIdx.x;
    const int bt   = blockIdx.x;     // 0..7 batch tile
    const int jblk = blockIdx.y;     // 0..15 col block
    const int b0   = bt * 32;
    const int wid  = tid >> 6;
    const int ln   = tid & 63;
    const int row  = b0 + (ln & 31);
    const int khi  = (ln >> 5) * 8;
    int* cnt = bar + bt * 16;        // group counter, 64B-spaced

    // B fragments -> registers, once.
    bf16x8 bh[33], bx[9];
    if (wid < 3) {
        const bf16x8* bH = (const bf16x8*)whf + ((jblk * 3 + wid) * 33) * 64 + ln;
        #pragma unroll
        for (int kc = 0; kc < 33; ++kc) bh[kc] = bH[kc * 64];
        const bf16x8* bX = (const bf16x8*)wxf + ((jblk * 3 + wid) * 9) * 64 + ln;
        #pragma unroll
        for (int kc = 0; kc < 9; ++kc) bx[kc] = bX[kc * 64];
    }

    int lens[4];                     // epilogue rows: (tid>>5) + 8u
    #pragma unroll
    for (int u = 0; u < 4; ++u) lens[u] = lengths[b0 + (tid >> 5) + 8 * u];

    // prefetch x A-frags for t=0
    bf16x8 ax[9];
    if (wid < 3) {
        const bf16x8* aX = (const bf16x8*)(x16 + (size_t)row * XKP + khi);
        #pragma unroll
        for (int kc = 0; kc < 9; ++kc) ax[kc] = aX[kc * 2];
    }

    for (int t = 0; t < TT; ++t) {
        const __hip_bfloat16* hprev = (t == 0) ? h0p : (hist + (size_t)(t - 1) * BB * HKP);
        __hip_bfloat16* hout = hist + (size_t)t * BB * HKP;

        if (wid < 3) {
            f32x16 accHa = {}, accHb = {}, accX = {};
            const bf16x8* aH = (const bf16x8*)(hprev + (size_t)row * HKP + khi);
            #pragma unroll
            for (int kc = 0; kc < 32; kc += 2) {
                accHa = __builtin_amdgcn_mfma_f32_32x32x16_bf16(aH[kc * 2], bh[kc], accHa, 0, 0, 0);
                accHb = __builtin_amdgcn_mfma_f32_32x32x16_bf16(aH[(kc + 1) * 2], bh[kc + 1], accHb, 0, 0, 0);
            }
            accHa = __builtin_amdgcn_mfma_f32_32x32x16_bf16(aH[32 * 2], bh[32], accHa, 0, 0, 0);
            #pragma unroll
            for (int kc = 0; kc < 9; ++kc)
                accX = __builtin_amdgcn_mfma_f32_32x32x16_bf16(ax[kc], bx[kc], accX, 0, 0, 0);

            const int col = ln & 31;
            const int rh = 4 * (ln >> 5);
            if (wid < 2) {
                f32x16 s = accHa + accHb + accX;
                #pragma unroll
                for (int r = 0; r < 16; ++r)
                    p[wid][(r & 3) + 8 * (r >> 2) + rh][col] = s[r];
            } else {
                f32x16 sh = accHa + accHb;
                #pragma unroll
                for (int r = 0; r < 16; ++r) {
                    int rr = (r & 3) + 8 * (r >> 2) + rh;
                    p[2][rr][col] = accX[r];   // xn (+ b_ih_n)
                    p[3][rr][col] = sh[r];     // hn (+ b_hh_n)
                }
            }
        }
        __syncthreads();

        {   // gate epilogue: 256 threads x 4 elems of the 32x32 tile
            const int j = tid & 31;
            const int r0 = tid >> 5;
            const int gj = jblk * 32 + j;
            #pragma unroll
            for (int u = 0; u < 4; ++u) {
                int br = r0 + u * 8;
                int b = b0 + br;
                float rr = sigm(p[0][br][j]);
                float zz = sigm(p[1][br][j]);
                float nn = tanhf(p[2][br][j] + rr * p[3][br][j]);
                float hp = __bfloat162float(hprev[(size_t)b * HKP + gj]);
                float hv = (t < lens[u]) ? ((1.f - zz) * nn + zz * hp) : hp;
                hout[(size_t)b * HKP + gj] = __float2bfloat16(hv);
            }
            if (jblk == 0) {          // bias-1 + zero pad cols 512..527
                int br = tid >> 3;
                int c = (tid & 7) * 2;
                hout[(size_t)(b0 + br) * HKP + HH + c]     = __float2bfloat16(c == 0 ? 1.0f : 0.0f);
                hout[(size_t)(b0 + br) * HKP + HH + c + 1] = __float2bfloat16(0.0f);
            }
        }
        __syncthreads();              // drains vmcnt: all stores in L2 before signal

        if (t < TT - 1) {
            if (tid == 0) {
                __threadfence();      // push this block's hist writes device-visible
                atomicAdd(cnt, 1);
            }
            // prefetch next x A-frags while thread0 waits on the group
            if (wid < 3) {
                const bf16x8* aX = (const bf16x8*)(x16 + ((size_t)(t + 1) * BB + row) * XKP + khi);
                #pragma unroll
                for (int kc = 0; kc < 9; ++kc) ax[kc] = aX[kc * 2];
            }
            if (tid == 0) {
                while (__hip_atomic_load(cnt, __ATOMIC_RELAXED, __HIP_MEMORY_SCOPE_AGENT) < 16 * (t + 1))
                    __builtin_amdgcn_s_sleep(2);
                __threadfence();      // acquire: no stale lines before reading hist[t]
            }
            __syncthreads();
        }
    }
}

// Fused 2-layer MLP head (fp32 compute, bf16 hidden-state reads).
__global__ __launch_bounds__(256) void head_kernel(
    const float* __restrict__ x,
    const __hip_bfloat16* __restrict__ hist,
    const float* __restrict__ w1T,
    const float* __restrict__ w2T,
    const float* __restrict__ b1,
    const float* __restrict__ b2,
    const int* __restrict__ lengths,
    float* __restrict__ out)
{
    __shared__ float pre[16][260];
    const int tid = threadIdx.x;
    const int r0 = blockIdx.x * 16;

    const int cg = tid & 63;
    const int rg = tid >> 6;

    const __hip_bfloat16* arow[4];
    float tdv[4];
    #pragma unroll
    for (int i = 0; i < 4; ++i) {
        int r = r0 + rg + (i << 2);
        int b = r / 255;
        int t = r - b * 255;
        arow[i] = hist + ((size_t)t * BB + b) * HKP;
        tdv[i] = x[((size_t)(t + 1) * BB + b) * DP1] - x[((size_t)t * BB + b) * DP1];
    }

    const int dg = tid & 31;
    const int rg2 = tid >> 5;
    float acc2[2][4] = {{0.f, 0.f, 0.f, 0.f}, {0.f, 0.f, 0.f, 0.f}};

    const float4* w1T4 = (const float4*)w1T;
    const float4* w2T4 = (const float4*)w2T;

    for (int kcb = 0; kcb < K1; kcb += 256) {
        float4 s0 = {0, 0, 0, 0}, s1 = {0, 0, 0, 0}, s2 = {0, 0, 0, 0}, s3 = {0, 0, 0, 0};
        const int col4 = (kcb >> 2) + cg;
        #pragma unroll 2
        for (int k = 0; k < HH; ++k) {
            float4 w = w1T4[k * 320 + col4];
            float a0 = __bfloat162float(arow[0][k]);
            float a1v = __bfloat162float(arow[1][k]);
            float a2 = __bfloat162float(arow[2][k]);
            float a3 = __bfloat162float(arow[3][k]);
            s0.x += a0 * w.x;  s0.y += a0 * w.y;  s0.z += a0 * w.z;  s0.w += a0 * w.w;
            s1.x += a1v * w.x; s1.y += a1v * w.y; s1.z += a1v * w.z; s1.w += a1v * w.w;
            s2.x += a2 * w.x;  s2.y += a2 * w.y;  s2.z += a2 * w.z;  s2.w += a2 * w.w;
            s3.x += a3 * w.x;  s3.y += a3 * w.y;  s3.z += a3 * w.z;  s3.w += a3 * w.w;
        }
        {   // td column (k = 512)
            float4 w = w1T4[512 * 320 + col4];
            s0.x += tdv[0] * w.x; s0.y += tdv[0] * w.y; s0.z += tdv[0] * w.z; s0.w += tdv[0] * w.w;
            s1.x += tdv[1] * w.x; s1.y += tdv[1] * w.y; s1.z += tdv[1] * w.z; s1.w += tdv[1] * w.w;
            s2.x += tdv[2] * w.x; s2.y += tdv[2] * w.y; s2.z += tdv[2] * w.z; s2.w += tdv[2] * w.w;
            s3.x += tdv[3] * w.x; s3.y += tdv[3] * w.y; s3.z += tdv[3] * w.z; s3.w += tdv[3] * w.w;
        }
        const int c = kcb + (cg << 2);
        float4 bb = *(const float4*)(b1 + c);
        float4 pv;
        pv.x = sigm(s0.x + bb.x); pv.y = sigm(s0.y + bb.y); pv.z = sigm(s0.z + bb.z); pv.w = sigm(s0.w + bb.w);
        *(float4*)&pre[rg][cg << 2] = pv;
        pv.x = sigm(s1.x + bb.x); pv.y = sigm(s1.y + bb.y); pv.z = sigm(s1.z + bb.z); pv.w = sigm(s1.w + bb.w);
        *(float4*)&pre[rg + 4][cg << 2] = pv;
        pv.x = sigm(s2.x + bb.x); pv.y = sigm(s2.y + bb.y); pv.z = sigm(s2.z + bb.z); pv.w = sigm(s2.w + bb.w);
        *(float4*)&pre[rg + 8][cg << 2] = pv;
        pv.x = sigm(s3.x + bb.x); pv.y = sigm(s3.y + bb.y); pv.z = sigm(s3.z + bb.z); pv.w = sigm(s3.w + bb.w);
        *(float4*)&pre[rg + 12][cg << 2] = pv;
        __syncthreads();

        for (int kk = 0; kk < 256; kk += 4) {
            float4 p0 = *(const float4*)&pre[rg2][kk];
            float4 p1 = *(const float4*)&pre[rg2 + 8][kk];
            float pav[4] = {p0.x, p0.y, p0.z, p0.w};
            float pbv[4] = {p1.x, p1.y, p1.z, p1.w};
            #pragma unroll
            for (int i = 0; i < 4; ++i) {
                float4 w = w2T4[(size_t)(kcb + kk + i) * 32 + dg];
                float pa = pav[i], pb = pbv[i];
                acc2[0][0] += pa * w.x; acc2[0][1] += pa * w.y; acc2[0][2] += pa * w.z; acc2[0][3] += pa * w.w;
                acc2[1][0] += pb * w.x; acc2[1][1] += pb * w.y; acc2[1][2] += pb * w.z; acc2[1][3] += pb * w.w;
            }
        }
        __syncthreads();
    }

    #pragma unroll
    for (int u = 0; u < 2; ++u) {
        int r = r0 + rg2 + (u << 3);
        int b = r / 255;
        int t = r - b * 255;
        bool valid = t < (lengths[b] - 1);
        int d = dg << 2;
        float4 bb = *(const float4*)(b2 + d);
        float4 o;
        o.x = valid ? (acc2[u][0] + bb.x) : 0.f;
        o.y = valid ? (acc2[u][1] + bb.y) : 0.f;
        o.z = valid ? (acc2[u][2] + bb.z) : 0.f;
        o.w = valid ? (acc2[u][3] + bb.w) : 0.f;
        *(float4*)(out + (size_t)r * DD + d) = o;
    }
}

__global__ __launch_bounds__(256) void tail_kernel(
    const __hip_bfloat16* __restrict__ hist,
    const float* __restrict__ wp,
    const float* __restrict__ bp,
    const int* __restrict__ lengths,
    float* __restrict__ out)
{
    int gid = blockIdx.x * 256 + threadIdx.x;
    if (gid < 768) {
        int b = gid / 3, pidx = gid - b * 3;
        float acc = bp[pidx];
        const __hip_bfloat16* hr = hist + ((size_t)(TT - 1) * BB + b) * HKP;
        const float* wr = wp + (size_t)pidx * HH;
        #pragma unroll 4
        for (int k = 0; k < HH; ++k) acc += __bfloat162float(hr[k]) * wr[k];
        out[OUT_DIST + gid] = __expf(-acc);
    } else if (gid < 1024) {
        int b = gid - 768;
        out[OUT_LEN + b] = (float)lengths[b];
    }
}

extern "C" void kernel_launch(void* const* d_in, const int* in_sizes, int n_in,
                              void* d_out, int out_size, void* d_ws, size_t ws_size,
                              hipStream_t stream)
{
    const float* x       = (const float*)d_in[0];
    const float* h0      = (const float*)d_in[1];
    const int*   lengths = (const int*)d_in[2];
    const float* w_ih    = (const float*)d_in[3];
    const float* w_hh    = (const float*)d_in[4];
    const float* b_ih    = (const float*)d_in[5];
    const float* b_hh    = (const float*)d_in[6];
    const float* w1      = (const float*)d_in[7];
    const float* b1      = (const float*)d_in[8];
    const float* w2      = (const float*)d_in[9];
    const float* b2      = (const float*)d_in[10];
    const float* wp      = (const float*)d_in[11];
    const float* bp      = (const float*)d_in[12];
    float* out = (float*)d_out;
    float* ws  = (float*)d_ws;

    __hip_bfloat16* bf   = (__hip_bfloat16*)(ws + F_END);
    __hip_bfloat16* x16  = bf + U_X16;
    __hip_bfloat16* whf  = bf + U_WHF;
    __hip_bfloat16* wxf  = bf + U_WXF;
    __hip_bfloat16* h16i = bf + U_H0;
    __hip_bfloat16* hist = bf + U_HIST;
    int* bar             = (int*)(bf + U_BAR);

    prep_kernel<<<44631, 256, 0, stream>>>(x, h0, w_ih, w_hh, b_ih, b_hh, w1, w2, ws);

    gru_scan<<<dim3(8, 16), 256, 0, stream>>>(x16, h16i, hist, whf, wxf, lengths, bar);

    head_kernel<<<RTOT / 16, 256, 0, stream>>>(x, hist, ws + OFF_W1T, ws + OFF_W2T,
                                               b1, b2, lengths, out);

    tail_kernel<<<4, 256, 0, stream>>>(hist, wp, bp, lengths, out);
}

// Round 5
// 2926.913 us; speedup vs baseline: 2.0002x; 2.0002x over previous
//
#include <hip/hip_runtime.h>
#include <hip/hip_bf16.h>
#include <math.h>

#define TT 256
#define BB 256
#define DP1 129
#define HH 512
#define K1 1280
#define DD 128
#define RTOT 65280   // B*(T-1)
#define XKP 144      // padded x-part K (129 feats + 1 bias + 14 zero)
#define HKP 528      // padded h-part K (512 h + 1 bias@512 + td@513 + zeros)

// ---- ws layout: all bf16 now, base = (bf16*)ws ----
#define U_X16   0            // 65536*144
#define U_WHF   9437184      // 48*33*512
#define U_WXF   10248192     // 48*9*512
#define U_H0    10469376     // 256*528
#define U_BAR   10604544     // 128 ints (as 256 bf16 slots)
#define U_W1P   10604800     // 40 tiles * 33 kc * 512   (K=528, cols 1280)
#define U_W2P   11280640     // 4 tiles * 80 kc * 512    (K=1280, cols 128)
#define U_HIST  11444480     // 256*256*528
#define PREP_N  11444480
// out layout (floats)
#define OUT_DIST 8355840     // 256*255*128
#define OUT_LEN  8356608

typedef __attribute__((ext_vector_type(8))) short bf16x8;
typedef __attribute__((ext_vector_type(16))) float f32x16;

__device__ __forceinline__ float sigm(float v) { return 1.0f / (1.0f + __expf(-v)); }

// One-time pack: bf16 x (+bias col), GRU weights as MFMA B-frags (biases folded
// as constant-1 K rows), h0, barrier init, and head weights as MFMA B-frags:
// w1p K=528 (k=512 -> b1, k=513 -> td coefficient w1[:,512]), w2p K=1280.
__global__ __launch_bounds__(256) void prep_kernel(
    const float* __restrict__ x, const float* __restrict__ h0,
    const float* __restrict__ w_ih, const float* __restrict__ w_hh,
    const float* __restrict__ b_ih, const float* __restrict__ b_hh,
    const float* __restrict__ w1, const float* __restrict__ b1,
    const float* __restrict__ w2,
    __hip_bfloat16* __restrict__ bf)
{
    int i = blockIdx.x * 256 + threadIdx.x;
    if (i < 9437184) {                        // x16: (t*B+b, 144)
        int tb = i / XKP, k = i - tb * XKP;
        float v = (k < DP1) ? x[(size_t)tb * DP1 + k] : (k == DP1 ? 1.0f : 0.0f);
        bf[U_X16 + i] = __float2bfloat16(v);
    } else if (i < 10248192) {                // whf B-frags (K=528 incl b_hh row)
        int r = i - 9437184;
        int e = r & 7;
        int lane = (r >> 3) & 63;
        int rem = r >> 9;
        int kc = rem % 33, gi = rem / 33;
        int jb = gi / 3, g = gi - jb * 3;
        int j = jb * 32 + (lane & 31);
        int k = kc * 16 + (lane >> 5) * 8 + e;
        float v = (k < HH) ? w_hh[(size_t)(g * HH + j) * HH + k]
                : (k == HH ? b_hh[g * HH + j] : 0.0f);
        bf[U_WHF + r] = __float2bfloat16(v);
    } else if (i < 10469376) {                // wxf B-frags (K=144 incl b_ih row)
        int r = i - 10248192;
        int e = r & 7;
        int lane = (r >> 3) & 63;
        int rem = r >> 9;
        int kc = rem % 9, gi = rem / 9;
        int jb = gi / 3, g = gi - jb * 3;
        int j = jb * 32 + (lane & 31);
        int k = kc * 16 + (lane >> 5) * 8 + e;
        float v = (k < DP1) ? w_ih[(size_t)(g * HH + j) * DP1 + k]
                : (k == DP1 ? b_ih[g * HH + j] : 0.0f);
        bf[U_WXF + r] = __float2bfloat16(v);
    } else if (i < 10604544) {                // h0 padded (B, 528)
        int r = i - 10469376;
        int b = r / HKP, k = r - b * HKP;
        float v = (k < HH) ? h0[(size_t)b * HH + k] : (k == HH ? 1.0f : 0.0f);
        bf[U_H0 + r] = __float2bfloat16(v);
    } else if (i < 10604800) {                // zero barrier counters
        int idx = i - 10604544;
        if (idx < 128) ((int*)(bf + U_BAR))[idx] = 0;
    } else if (i < 11280640) {                // w1p B-frags (40 tiles, 33 kc)
        int r = i - 10604800;
        int e = r & 7;
        int lane = (r >> 3) & 63;
        int rem = r >> 9;
        int kc = rem % 33, tile = rem / 33;
        int col = tile * 32 + (lane & 31);
        int k = kc * 16 + (lane >> 5) * 8 + e;
        float v = (k < HH) ? w1[(size_t)col * 513 + k]
                : (k == HH ? b1[col]
                : (k == HH + 1 ? w1[(size_t)col * 513 + 512] : 0.0f));
        bf[U_W1P + r] = __float2bfloat16(v);
    } else if (i < PREP_N) {                  // w2p B-frags (4 tiles, 80 kc)
        int r = i - 11280640;
        int e = r & 7;
        int lane = (r >> 3) & 63;
        int rem = r >> 9;
        int kc = rem % 80, tile = rem / 80;
        int col = tile * 32 + (lane & 31);
        int k = kc * 16 + (lane >> 5) * 8 + e;
        bf[U_W2P + r] = __float2bfloat16(w2[(size_t)col * K1 + k]);
    }
}

// Persistent GRU scan (unchanged from round 4): grid (8 bt, 16 jblk) = 128
// blocks, B-frags in registers, group-scoped monotone atomic barrier.
__global__ __launch_bounds__(256, 1) void gru_scan(
    const __hip_bfloat16* __restrict__ x16,
    const __hip_bfloat16* __restrict__ h0p,
    __hip_bfloat16* __restrict__ hist,
    const __hip_bfloat16* __restrict__ whf,
    const __hip_bfloat16* __restrict__ wxf,
    const int* __restrict__ lengths,
    int* __restrict__ bar)
{
    __shared__ float p[4][32][33];
    const int tid  = threadIdx.x;
    const int bt   = blockIdx.x;
    const int jblk = blockIdx.y;
    const int b0   = bt * 32;
    const int wid  = tid >> 6;
    const int ln   = tid & 63;
    const int row  = b0 + (ln & 31);
    const int khi  = (ln >> 5) * 8;
    int* cnt = bar + bt * 16;

    bf16x8 bh[33], bx[9];
    if (wid < 3) {
        const bf16x8* bH = (const bf16x8*)whf + ((jblk * 3 + wid) * 33) * 64 + ln;
        #pragma unroll
        for (int kc = 0; kc < 33; ++kc) bh[kc] = bH[kc * 64];
        const bf16x8* bX = (const bf16x8*)wxf + ((jblk * 3 + wid) * 9) * 64 + ln;
        #pragma unroll
        for (int kc = 0; kc < 9; ++kc) bx[kc] = bX[kc * 64];
    }

    int lens[4];
    #pragma unroll
    for (int u = 0; u < 4; ++u) lens[u] = lengths[b0 + (tid >> 5) + 8 * u];

    bf16x8 ax[9];
    if (wid < 3) {
        const bf16x8* aX = (const bf16x8*)(x16 + (size_t)row * XKP + khi);
        #pragma unroll
        for (int kc = 0; kc < 9; ++kc) ax[kc] = aX[kc * 2];
    }

    for (int t = 0; t < TT; ++t) {
        const __hip_bfloat16* hprev = (t == 0) ? h0p : (hist + (size_t)(t - 1) * BB * HKP);
        __hip_bfloat16* hout = hist + (size_t)t * BB * HKP;

        if (wid < 3) {
            f32x16 accHa = {}, accHb = {}, accX = {};
            const bf16x8* aH = (const bf16x8*)(hprev + (size_t)row * HKP + khi);
            #pragma unroll
            for (int kc = 0; kc < 32; kc += 2) {
                accHa = __builtin_amdgcn_mfma_f32_32x32x16_bf16(aH[kc * 2], bh[kc], accHa, 0, 0, 0);
                accHb = __builtin_amdgcn_mfma_f32_32x32x16_bf16(aH[(kc + 1) * 2], bh[kc + 1], accHb, 0, 0, 0);
            }
            accHa = __builtin_amdgcn_mfma_f32_32x32x16_bf16(aH[32 * 2], bh[32], accHa, 0, 0, 0);
            #pragma unroll
            for (int kc = 0; kc < 9; ++kc)
                accX = __builtin_amdgcn_mfma_f32_32x32x16_bf16(ax[kc], bx[kc], accX, 0, 0, 0);

            const int col = ln & 31;
            const int rh = 4 * (ln >> 5);
            if (wid < 2) {
                f32x16 s = accHa + accHb + accX;
                #pragma unroll
                for (int r = 0; r < 16; ++r)
                    p[wid][(r & 3) + 8 * (r >> 2) + rh][col] = s[r];
            } else {
                f32x16 sh = accHa + accHb;
                #pragma unroll
                for (int r = 0; r < 16; ++r) {
                    int rr = (r & 3) + 8 * (r >> 2) + rh;
                    p[2][rr][col] = accX[r];
                    p[3][rr][col] = sh[r];
                }
            }
        }
        __syncthreads();

        {
            const int j = tid & 31;
            const int r0 = tid >> 5;
            const int gj = jblk * 32 + j;
            #pragma unroll
            for (int u = 0; u < 4; ++u) {
                int br = r0 + u * 8;
                int b = b0 + br;
                float rr = sigm(p[0][br][j]);
                float zz = sigm(p[1][br][j]);
                float nn = tanhf(p[2][br][j] + rr * p[3][br][j]);
                float hp = __bfloat162float(hprev[(size_t)b * HKP + gj]);
                float hv = (t < lens[u]) ? ((1.f - zz) * nn + zz * hp) : hp;
                hout[(size_t)b * HKP + gj] = __float2bfloat16(hv);
            }
            if (jblk == 0) {
                int br = tid >> 3;
                int c = (tid & 7) * 2;
                hout[(size_t)(b0 + br) * HKP + HH + c]     = __float2bfloat16(c == 0 ? 1.0f : 0.0f);
                hout[(size_t)(b0 + br) * HKP + HH + c + 1] = __float2bfloat16(0.0f);
            }
        }
        __syncthreads();

        if (t < TT - 1) {
            if (tid == 0) {
                __threadfence();
                atomicAdd(cnt, 1);
            }
            if (wid < 3) {
                const bf16x8* aX = (const bf16x8*)(x16 + ((size_t)(t + 1) * BB + row) * XKP + khi);
                #pragma unroll
                for (int kc = 0; kc < 9; ++kc) ax[kc] = aX[kc * 2];
            }
            if (tid == 0) {
                while (__hip_atomic_load(cnt, __ATOMIC_RELAXED, __HIP_MEMORY_SCOPE_AGENT) < 16 * (t + 1))
                    __builtin_amdgcn_s_sleep(2);
                __threadfence();
            }
            __syncthreads();
        }
    }
}

// Write td into hist col 513 (after the scan) so the head's stage-1 is a pure
// K=528 GEMM over hist rows.
__global__ __launch_bounds__(256) void td_kernel(
    const float* __restrict__ x, __hip_bfloat16* __restrict__ hist)
{
    int r = blockIdx.x * 256 + threadIdx.x;
    if (r < RTOT) {
        int b = r / 255, t = r - b * 255;
        float td = x[((size_t)(t + 1) * BB + b) * DP1] - x[((size_t)t * BB + b) * DP1];
        hist[((size_t)t * BB + b) * HKP + 513] = __float2bfloat16(td);
    }
}

// MFMA head: block = 64 rows (2 row-tiles) x 4 waves, 1020 blocks.
// 5 chunks of 256 hidden cols: stage1 (K=528) MFMA -> sigmoid -> bf16 LDS;
// stage2 (K-chunk=256) MFMA accumulates all 128 output cols in registers.
__global__ __launch_bounds__(256) void head_mfma(
    const __hip_bfloat16* __restrict__ hist,
    const __hip_bfloat16* __restrict__ w1p,
    const __hip_bfloat16* __restrict__ w2p,
    const float* __restrict__ b2,
    const int* __restrict__ lengths,
    float* __restrict__ out)
{
    __shared__ __hip_bfloat16 preS[64 * 264];   // stride 264 (16B-aligned rows)
    const int tid = threadIdx.x;
    const int wv  = tid >> 6;
    const int ln  = tid & 63;
    const int r0  = blockIdx.x * 64;
    const int m   = ln & 31;
    const int khi = (ln >> 5) * 8;

    const __hip_bfloat16* aBase0;
    const __hip_bfloat16* aBase1;
    {
        int r = r0 + m;
        int b = r / 255, t = r - b * 255;
        aBase0 = hist + ((size_t)t * BB + b) * HKP + khi;
        r = r0 + 32 + m;
        b = r / 255; t = r - b * 255;
        aBase1 = hist + ((size_t)t * BB + b) * HKP + khi;
    }

    f32x16 acc20 = {}, acc21 = {};

    for (int c = 0; c < 5; ++c) {
        f32x16 s00 = {}, s01 = {}, s10 = {}, s11 = {};
        const int t0 = c * 8 + wv * 2;          // global col-tile (of 40)
        const bf16x8* bp0 = (const bf16x8*)w1p + ((size_t)t0 * 33) * 64 + ln;
        const bf16x8* bp1 = bp0 + 33 * 64;
        #pragma unroll 4
        for (int kc = 0; kc < 33; ++kc) {
            bf16x8 a0 = *(const bf16x8*)(aBase0 + kc * 16);
            bf16x8 a1 = *(const bf16x8*)(aBase1 + kc * 16);
            bf16x8 w0 = bp0[kc * 64];
            bf16x8 w1f = bp1[kc * 64];
            s00 = __builtin_amdgcn_mfma_f32_32x32x16_bf16(a0, w0, s00, 0, 0, 0);
            s01 = __builtin_amdgcn_mfma_f32_32x32x16_bf16(a0, w1f, s01, 0, 0, 0);
            s10 = __builtin_amdgcn_mfma_f32_32x32x16_bf16(a1, w0, s10, 0, 0, 0);
            s11 = __builtin_amdgcn_mfma_f32_32x32x16_bf16(a1, w1f, s11, 0, 0, 0);
        }
        // sigmoid -> LDS (bf16). C layout: row=(reg&3)+8*(reg>>2)+4*(ln>>5), col=m.
        const int colL = wv * 64 + m;
        const int rb = 4 * (ln >> 5);
        #pragma unroll
        for (int reg = 0; reg < 16; ++reg) {
            int rr = (reg & 3) + 8 * (reg >> 2) + rb;
            preS[rr * 264 + colL]            = __float2bfloat16(sigm(s00[reg]));
            preS[rr * 264 + colL + 32]       = __float2bfloat16(sigm(s01[reg]));
            preS[(rr + 32) * 264 + colL]     = __float2bfloat16(sigm(s10[reg]));
            preS[(rr + 32) * 264 + colL + 32]= __float2bfloat16(sigm(s11[reg]));
        }
        __syncthreads();

        // stage2: wave -> output col-tile wv; K-chunks c*16..c*16+15
        const bf16x8* b2p = (const bf16x8*)w2p + ((size_t)wv * 80 + c * 16) * 64 + ln;
        #pragma unroll 4
        for (int j = 0; j < 16; ++j) {
            bf16x8 pa0 = *(const bf16x8*)(preS + m * 264 + j * 16 + khi);
            bf16x8 pa1 = *(const bf16x8*)(preS + (32 + m) * 264 + j * 16 + khi);
            bf16x8 wb = b2p[j * 64];
            acc20 = __builtin_amdgcn_mfma_f32_32x32x16_bf16(pa0, wb, acc20, 0, 0, 0);
            acc21 = __builtin_amdgcn_mfma_f32_32x32x16_bf16(pa1, wb, acc21, 0, 0, 0);
        }
        __syncthreads();
    }

    const int d = wv * 32 + m;
    const float bias = b2[d];
    const int rb = 4 * (ln >> 5);
    #pragma unroll
    for (int reg = 0; reg < 16; ++reg) {
        int rr = (reg & 3) + 8 * (reg >> 2) + rb;
        {
            int r = r0 + rr;
            int b = r / 255, t = r - b * 255;
            bool valid = t < (lengths[b] - 1);
            out[(size_t)r * DD + d] = valid ? (acc20[reg] + bias) : 0.f;
        }
        {
            int r = r0 + 32 + rr;
            int b = r / 255, t = r - b * 255;
            bool valid = t < (lengths[b] - 1);
            out[(size_t)r * DD + d] = valid ? (acc21[reg] + bias) : 0.f;
        }
    }
}

__global__ __launch_bounds__(256) void tail_kernel(
    const __hip_bfloat16* __restrict__ hist,
    const float* __restrict__ wp,
    const float* __restrict__ bp,
    const int* __restrict__ lengths,
    float* __restrict__ out)
{
    int gid = blockIdx.x * 256 + threadIdx.x;
    if (gid < 768) {
        int b = gid / 3, pidx = gid - b * 3;
        float acc = bp[pidx];
        const __hip_bfloat16* hr = hist + ((size_t)(TT - 1) * BB + b) * HKP;
        const float* wr = wp + (size_t)pidx * HH;
        #pragma unroll 4
        for (int k = 0; k < HH; ++k) acc += __bfloat162float(hr[k]) * wr[k];
        out[OUT_DIST + gid] = __expf(-acc);
    } else if (gid < 1024) {
        int b = gid - 768;
        out[OUT_LEN + b] = (float)lengths[b];
    }
}

extern "C" void kernel_launch(void* const* d_in, const int* in_sizes, int n_in,
                              void* d_out, int out_size, void* d_ws, size_t ws_size,
                              hipStream_t stream)
{
    const float* x       = (const float*)d_in[0];
    const float* h0      = (const float*)d_in[1];
    const int*   lengths = (const int*)d_in[2];
    const float* w_ih    = (const float*)d_in[3];
    const float* w_hh    = (const float*)d_in[4];
    const float* b_ih    = (const float*)d_in[5];
    const float* b_hh    = (const float*)d_in[6];
    const float* w1      = (const float*)d_in[7];
    const float* b1      = (const float*)d_in[8];
    const float* w2      = (const float*)d_in[9];
    const float* b2      = (const float*)d_in[10];
    const float* wp      = (const float*)d_in[11];
    const float* bp      = (const float*)d_in[12];
    float* out = (float*)d_out;

    __hip_bfloat16* bf   = (__hip_bfloat16*)d_ws;
    __hip_bfloat16* x16  = bf + U_X16;
    __hip_bfloat16* whf  = bf + U_WHF;
    __hip_bfloat16* wxf  = bf + U_WXF;
    __hip_bfloat16* h16i = bf + U_H0;
    __hip_bfloat16* w1p  = bf + U_W1P;
    __hip_bfloat16* w2p  = bf + U_W2P;
    __hip_bfloat16* hist = bf + U_HIST;
    int* bar             = (int*)(bf + U_BAR);

    prep_kernel<<<(PREP_N + 255) / 256, 256, 0, stream>>>(
        x, h0, w_ih, w_hh, b_ih, b_hh, w1, b1, w2, bf);

    gru_scan<<<dim3(8, 16), 256, 0, stream>>>(x16, h16i, hist, whf, wxf, lengths, bar);

    td_kernel<<<(RTOT + 255) / 256, 256, 0, stream>>>(x, hist);

    head_mfma<<<RTOT / 64, 256, 0, stream>>>(hist, w1p, w2p, b2, lengths, out);

    tail_kernel<<<4, 256, 0, stream>>>(hist, wp, bp, lengths, out);
}